// Round 6
// baseline (3228.599 us; speedup 1.0000x reference)
//
#include <hip/hip_runtime.h>

#define NEGF (-1e30f)

typedef __attribute__((ext_vector_type(8))) short short8;
typedef __attribute__((ext_vector_type(4))) float float4v;

template <bool V> struct BC { static constexpr bool value = V; };

__device__ __forceinline__ short f2bf(float f) {
  union { float f; unsigned u; } v; v.f = f;
  unsigned r = v.u + 0x7fffu + ((v.u >> 16) & 1u);  // RNE truncate to bf16
  return (short)(r >> 16);
}
__device__ __forceinline__ float fastrcp(float x) { return __builtin_amdgcn_rcpf(x); }
__device__ __forceinline__ float sigf(float x) { return fastrcp(1.0f + __expf(-x)); }
__device__ __forceinline__ float tanhfast(float x) { return 1.0f - 2.0f * fastrcp(__expf(2.0f * x) + 1.0f); }

// ---------------------------------------------------------------------------
// prep: stage Wcat = [Wh1;Wh2] (256x640 f32) into bf16 MFMA B-fragment layout.
__global__ void prep_w_kernel(const float* __restrict__ Wh1, const float* __restrict__ Wh2,
                              short* __restrict__ wsW) {
  int t = blockIdx.x * 256 + threadIdx.x;   // 0..20479
  int lane = t & 63;
  int frag = t >> 6;                        // 0..319
  int nt = frag >> 3, kk = frag & 7;
  int n  = nt * 16 + (lane & 15);
  int kb = kk * 32 + (lane >> 4) * 8;
  short8 v;
#pragma unroll
  for (int j = 0; j < 8; ++j) {
    int k = kb + j;
    float w = (k < 128) ? Wh1[k * 640 + n] : Wh2[(k - 128) * 640 + n];
    v[j] = f2bf(w);
  }
  ((short8*)wsW)[frag * 64 + lane] = v;
}

// ---------------------------------------------------------------------------
// MDLSTM wavefront kernel: TWO batches per block (16 blocks, 8 waves).
// R2-R5 established the 128-VGPR compiler target is immovable -> weights
// stream from L2 every diagonal (~320 KB/CU/diag, the dominant cost).
// Amortize it: each weight fragment load now feeds 4 MFMAs (2 mt x 2 batch).
// c-state lives in registers (c_left = own lane prev; c_up via shfl),
// h double-buffered in LDS -> exactly ONE barrier per diagonal.
__global__ __launch_bounds__(512)
void mdlstm_kernel(const float* __restrict__ X, const short* __restrict__ wsW,
                   const float* __restrict__ Wx, const float* __restrict__ bias,
                   float* __restrict__ feat) {
  __shared__ __align__(16) short h_buf[2][2][32][136];  // [buf][batch][row][col]
  __shared__ float Xs[2][8192];                         // X for both batches

  const int tid  = threadIdx.x;
  const int lane = tid & 63;
  const int g    = tid >> 6;       // wave 0..7
  const int col  = lane & 15;
  const int quad = lane >> 4;
  const int jj   = g * 16 + col;   // h-feature column this lane owns
  const int b0   = blockIdx.x * 2;

  // zero-init h (boundary h=0 for w<0 / row<0) and this block's feat slice
  for (int i = tid; i < 2 * 2 * 32 * 136 / 2; i += 512) ((int*)h_buf)[i] = 0;
  {
    float4 z4 = {0.f, 0.f, 0.f, 0.f};
    float4* f4 = (float4*)(feat + b0 * 32768);
    for (int i = tid; i < 16384; i += 512) f4[i] = z4;   // 2 batches x 256x128
    const float4* Xb4 = (const float4*)(X + b0 * 8192);
    for (int i = tid; i < 4096; i += 512) ((float4*)Xs)[i] = Xb4[i];
  }

  float wx[5], bg[5];
#pragma unroll
  for (int q = 0; q < 5; ++q) {
    wx[q] = Wx[q * 128 + jj];
    bg[q] = bias[q * 128 + jj];
  }
  float cp[2][2][4];   // c state in registers: [batch][mt][r]
#pragma unroll
  for (int bb = 0; bb < 2; ++bb)
#pragma unroll
    for (int mt = 0; mt < 2; ++mt)
#pragma unroll
      for (int r = 0; r < 4; ++r) cp[bb][mt][r] = 0.0f;

  float* featb[2] = {feat + b0 * 32768, feat + (b0 + 1) * 32768};
  const short8* W8 = (const short8*)wsW;
  const int col48 = col + 48;
  __syncthreads();

  auto step = [&](int d, auto c0, auto c1) {
    constexpr bool DO0 = decltype(c0)::value;   // rows 0..15 active
    constexpr bool DO1 = decltype(c1)::value;   // rows 16..31 active
    const int rbuf = (d + 1) & 1, wbuf = d & 1;

    float4v acc[5][2][2];  // [gate][batch][mt], bias folded into init
#pragma unroll
    for (int q = 0; q < 5; ++q)
#pragma unroll
      for (int bb = 0; bb < 2; ++bb) {
        if (DO0) acc[q][bb][0] = (float4v){bg[q], bg[q], bg[q], bg[q]};
        if (DO1) acc[q][bb][1] = (float4v){bg[q], bg[q], bg[q], bg[q]};
      }
    const short8 z8 = (short8){0, 0, 0, 0, 0, 0, 0, 0};
#pragma unroll
    for (int kk = 0; kk < 8; ++kk) {
      const int kb = kk * 32 + quad * 8;
      const int up = (kb >= 128) ? 1 : 0;   // k<128: left neighbor; else: up
      const int cc = kb & 127;
      short8 a[2][2];
#pragma unroll
      for (int bb = 0; bb < 2; ++bb) {
        if (DO0) {
          int row = col - up;
          a[bb][0] = (row >= 0) ? *(const short8*)&h_buf[rbuf][bb][row][cc] : z8;
        }
        if (DO1) {
          int row = 16 + col - up;
          a[bb][1] = *(const short8*)&h_buf[rbuf][bb][row][cc];
        }
      }
#pragma unroll
      for (int q = 0; q < 5; ++q) {
        short8 bf = W8[((q * 8 + g) * 8 + kk) * 64 + lane];  // 1 load -> 4 MFMAs
#pragma unroll
        for (int bb = 0; bb < 2; ++bb) {
          if (DO0) acc[q][bb][0] = __builtin_amdgcn_mfma_f32_16x16x32_bf16(a[bb][0], bf, acc[q][bb][0], 0, 0, 0);
          if (DO1) acc[q][bb][1] = __builtin_amdgcn_mfma_f32_16x16x32_bf16(a[bb][1], bf, acc[q][bb][1], 0, 0, 0);
        }
      }
    }

    // ---- epilogue (no barrier needed before it: h write-buf != read-buf) ----
#pragma unroll
    for (int bb = 0; bb < 2; ++bb) {
      // capture ALL old-c cross-row values before any update
      float t0 = __shfl_up(cp[bb][0][3], 16);          // quad-1's mt0 r3
      float t1 = __shfl_up(cp[bb][1][3], 16);          // quad-1's mt1 r3
      float tx = __shfl(cp[bb][0][3], col48);          // quad3's mt0 r3 (row 15)
      float cuA[4] = {quad ? t0 : 0.0f, cp[bb][0][0], cp[bb][0][1], cp[bb][0][2]};
      float cuB[4] = {quad ? t1 : tx,   cp[bb][1][0], cp[bb][1][1], cp[bb][1][2]};
      float* fb = featb[bb];
#pragma unroll
      for (int mt = 0; mt < 2; ++mt) {
        if ((mt == 0 && !DO0) || (mt == 1 && !DO1)) continue;
        const int m0 = mt * 16 + quad * 4;
        float fo[4];
#pragma unroll
        for (int r = 0; r < 4; ++r) {
          int w = d - (m0 + r);
          fo[r] = (w >= 0 && w < 256) ? fb[w * 128 + jj] : 0.0f;  // early L2 load
        }
#pragma unroll
        for (int r = 0; r < 4; ++r) {
          const int m = m0 + r;          // C/D layout: row = quad*4 + reg
          const int w = d - m;
          if (w >= 0 && w < 256) {
            float c_up = mt ? cuB[r] : cuA[r];
            float c_l  = cp[bb][mt][r];
            float xm = Xs[bb][w * 32 + m];
            float zi = fmaf(xm, wx[0], acc[0][bb][mt][r]);
            float zg = fmaf(xm, wx[1], acc[1][bb][mt][r]);
            float z1 = fmaf(xm, wx[2], acc[2][bb][mt][r]);
            float z2 = fmaf(xm, wx[3], acc[3][bb][mt][r]);
            float zo = fmaf(xm, wx[4], acc[4][bb][mt][r]);
            float c = sigf(z1) * c_l + sigf(z2) * c_up + sigf(zi) * tanhfast(zg);
            float h = sigf(zo) * tanhfast(c);
            cp[bb][mt][r] = c;
            h_buf[wbuf][bb][m][jj] = f2bf(h);
            fb[w * 128 + jj] = fo[r] + h;   // unique (w,jj) per lane per diag
          }
        }
      }
    }
  };

  BC<true> T; BC<false> F;
  for (int d = 0; d < 16; ++d)    { step(d, T, F); __syncthreads(); }
  for (int d = 16; d < 271; ++d)  { step(d, T, T); __syncthreads(); }
  for (int d = 271; d < 287; ++d) { step(d, F, T); __syncthreads(); }
}

// ---------------------------------------------------------------------------
// logits = feat @ W_fc + b_fc, then log_softmax -> logp [32][256][101]
__global__ __launch_bounds__(256)
void logits_kernel(const float* __restrict__ feat, const float* __restrict__ Wfc,
                   const float* __restrict__ bfc, float* __restrict__ logp) {
  __shared__ float sW[128 * 101];
  __shared__ float sF[8][128];
  __shared__ float sL[8][104];
  __shared__ float sLse[8];
  const int tid = threadIdx.x;
  const int b  = blockIdx.x >> 5;
  const int t0 = (blockIdx.x & 31) * 8;

  for (int i = tid; i < 128 * 101; i += 256) sW[i] = Wfc[i];
  for (int i = tid; i < 8 * 128; i += 256)
    sF[i >> 7][i & 127] = feat[(b * 256 + t0 + (i >> 7)) * 128 + (i & 127)];
  __syncthreads();
  for (int idx = tid; idx < 8 * 101; idx += 256) {
    int tr = idx / 101, v = idx - tr * 101;
    float s = bfc[v];
#pragma unroll 4
    for (int k = 0; k < 128; ++k) s += sF[tr][k] * sW[k * 101 + v];
    sL[tr][v] = s;
  }
  __syncthreads();
  if (tid < 8) {
    float m = NEGF;
    for (int v = 0; v < 101; ++v) m = fmaxf(m, sL[tid][v]);
    float su = 0.0f;
    for (int v = 0; v < 101; ++v) su += __expf(sL[tid][v] - m);
    sLse[tid] = m + __logf(su);
  }
  __syncthreads();
  for (int idx = tid; idx < 8 * 101; idx += 256) {
    int tr = idx / 101, v = idx - tr * 101;
    logp[(b * 256 + t0 + tr) * 101 + v] = sL[tr][v] - sLse[tr];
  }
}

// ---------------------------------------------------------------------------
// CTC forward: one wave per batch. Lane l holds alpha[s=l]; lane 63 also s=64.
__global__ __launch_bounds__(64)
void ctc_kernel(const float* __restrict__ logp, const int* __restrict__ y,
                float* __restrict__ out) {
  const int b = blockIdx.x;
  const int l = threadIdx.x;
  const float* lpb = logp + b * 256 * 101;
  const int* yb = y + b * 32;
  int lab = (l & 1) ? yb[l >> 1] : 100;                 // ext[s]: odd->label, even->blank
  bool skip = (l & 1) && (l >= 3) && (yb[l >> 1] != yb[(l >> 1) - 1]);

  float a   = (l == 0) ? lpb[100] : ((l == 1) ? lpb[lab] : NEGF);
  float a64 = NEGF;                                      // alpha[64] (valid on lane 63)
  float lpl = lpb[101 + lab];
  float lpbk = lpb[101 + 100];
  for (int t = 1; t < 256; ++t) {
    float nlpl = 0.0f, nlpbk = 0.0f;
    if (t < 255) {
      const float* lpn = lpb + (t + 1) * 101;
      nlpl = lpn[lab];
      nlpbk = lpn[100];
    }
    float am1 = __shfl_up(a, 1); if (l == 0) am1 = NEGF;
    float am2 = __shfl_up(a, 2); if (l < 2 || !skip) am2 = NEGF;
    float m3 = fmaxf(a, fmaxf(am1, am2));
    float na = m3 + __logf(__expf(a - m3) + __expf(am1 - m3) + __expf(am2 - m3)) + lpl;
    float m2 = fmaxf(a64, a);                            // s=64: lse(alpha64, alpha63)
    float na64 = m2 + __logf(__expf(a64 - m2) + __expf(a - m2)) + lpbk;
    a = na;
    a64 = na64;
    lpl = nlpl;
    lpbk = nlpbk;
  }
  float A63 = __shfl(a, 63);
  float A64 = __shfl(a64, 63);
  if (l == 0) {
    float m = fmaxf(A63, A64);
    out[b] = -(m + __logf(__expf(A63 - m) + __expf(A64 - m)));
  }
}

// ---------------------------------------------------------------------------
extern "C" void kernel_launch(void* const* d_in, const int* in_sizes, int n_in,
                              void* d_out, int out_size, void* d_ws, size_t ws_size,
                              hipStream_t stream) {
  const float* X   = (const float*)d_in[0];
  const int*   y   = (const int*)d_in[1];
  const float* Wx  = (const float*)d_in[2];
  const float* Wh1 = (const float*)d_in[3];
  const float* Wh2 = (const float*)d_in[4];
  const float* bi  = (const float*)d_in[5];
  const float* Wfc = (const float*)d_in[6];
  const float* bfc = (const float*)d_in[7];
  float* out = (float*)d_out;

  char* ws = (char*)d_ws;
  short* wsW  = (short*)(ws);              // 327,680 B staged weights
  float* feat = (float*)(ws + 0x50000);    // 4 MiB feat accumulator (zeroed in-kernel)
  float* logp = (float*)(ws + 0x450000);   // 3.31 MB log-probs

  prep_w_kernel<<<80, 256, 0, stream>>>(Wh1, Wh2, wsW);
  mdlstm_kernel<<<16, 512, 0, stream>>>(X, wsW, Wx, bi, feat);
  logits_kernel<<<1024, 256, 0, stream>>>(feat, Wfc, bfc, logp);
  ctc_kernel<<<32, 64, 0, stream>>>(logp, y, out);
}

// Round 7
// 983.526 us; speedup vs baseline: 3.2827x; 3.2827x over previous
//
#include <hip/hip_runtime.h>

#define NEGF (-1e30f)

typedef __attribute__((ext_vector_type(8))) short short8;
typedef __attribute__((ext_vector_type(4))) float float4v;

template <bool V> struct BC { static constexpr bool value = V; };

__device__ __forceinline__ short f2bf(float f) {
  union { float f; unsigned u; } v; v.f = f;
  unsigned r = v.u + 0x7fffu + ((v.u >> 16) & 1u);  // RNE truncate to bf16
  return (short)(r >> 16);
}
__device__ __forceinline__ float fastrcp(float x) { return __builtin_amdgcn_rcpf(x); }
__device__ __forceinline__ float sigf(float x) { return fastrcp(1.0f + __expf(-x)); }
__device__ __forceinline__ float tanhfast(float x) { return 1.0f - 2.0f * fastrcp(__expf(2.0f * x) + 1.0f); }

// ---------------------------------------------------------------------------
// prep: stage Wcat = [Wh1;Wh2] (256x640 f32) into bf16 MFMA B-fragment layout.
// frag f = q*64 + g*8 + kk; lane holds B[k][n], k=kk*32+(lane>>4)*8+j,
// n = (q*8+g)*16 + (lane&15); 16B per lane.
__global__ void prep_w_kernel(const float* __restrict__ Wh1, const float* __restrict__ Wh2,
                              short* __restrict__ wsW) {
  int t = blockIdx.x * 256 + threadIdx.x;   // 0..20479
  int lane = t & 63;
  int frag = t >> 6;                        // 0..319
  int nt = frag >> 3, kk = frag & 7;
  int n  = nt * 16 + (lane & 15);
  int kb = kk * 32 + (lane >> 4) * 8;
  short8 v;
#pragma unroll
  for (int j = 0; j < 8; ++j) {
    int k = kb + j;
    float w = (k < 128) ? Wh1[k * 640 + n] : Wh2[(k - 128) * 640 + n];
    v[j] = f2bf(w);
  }
  ((short8*)wsW)[frag * 64 + lane] = v;
}

// ---------------------------------------------------------------------------
// MDLSTM wavefront: 1 batch/block (32 blocks), 8 waves, 1 barrier/diagonal.
// 128-VGPR cap is immovable (R2-R6) -> design inside it:
//  - gates 0..2 weights stream from L2 (192 KB/diag, VMEM pipe)
//  - gates 3..4 weights cached in LDS (128 KB, read on LDS pipe) -> the two
//    streams run on DIFFERENT pipes instead of 320 KB serial on VMEM
//  - c-state in registers (shfl exchange), h double-buffered in LDS
//  - interior diagonals d in [31,255] compiled without bounds checks
__global__ __launch_bounds__(512)
void mdlstm_kernel(const float* __restrict__ X, const short* __restrict__ wsW,
                   const float* __restrict__ Wx, const float* __restrict__ bias,
                   float* __restrict__ feat) {
  __shared__ __align__(16) short h_buf[2][32][136];   // 17.4 KB: h double-buffer
  __shared__ __align__(16) short wlds[128 * 512];     // 128 KB: gates 3,4 frags

  const int b    = blockIdx.x;
  const int tid  = threadIdx.x;
  const int lane = tid & 63;
  const int g    = tid >> 6;       // wave 0..7
  const int col  = lane & 15;
  const int quad = lane >> 4;
  const int jj   = g * 16 + col;   // h-feature column this lane owns

  // zero h buffers (boundary h=0), stage gates 3,4 into LDS, zero feat slice
  for (int i = tid; i < 2 * 32 * 136 / 2; i += 512) ((int*)h_buf)[i] = 0;
  {
    const uint4* src = (const uint4*)(wsW + 192 * 512);  // frag 192 onward
    uint4* dst = (uint4*)wlds;
    for (int i = tid; i < 8192; i += 512) dst[i] = src[i];
  }
  {
    float4 z4 = {0.f, 0.f, 0.f, 0.f};
    float4* f4 = (float4*)(feat + b * 32768);
    for (int i = tid; i < 8192; i += 512) f4[i] = z4;
  }

  float wx[5], bg[5];
#pragma unroll
  for (int q = 0; q < 5; ++q) {
    wx[q] = Wx[q * 128 + jj];
    bg[q] = bias[q * 128 + jj];
  }
  float cp[2][4];   // c-state in registers: [mt][r], row = mt*16+quad*4+r
#pragma unroll
  for (int mt = 0; mt < 2; ++mt)
#pragma unroll
    for (int r = 0; r < 4; ++r) cp[mt][r] = 0.0f;

  const float* Xg = X + b * 8192;
  float* fb = feat + b * 32768;
  const short8* W8 = (const short8*)wsW;
  const int col48 = col + 48;
  __syncthreads();

  auto step = [&](int d, auto c0, auto c1, auto cv) {
    constexpr bool DO0 = decltype(c0)::value;   // rows 0..15 active
    constexpr bool DO1 = decltype(c1)::value;   // rows 16..31 active
    constexpr bool ALLV = decltype(cv)::value;  // all w in-range (no checks)
    const int rbuf = (d + 1) & 1, wbuf = d & 1;

    float4v acc[5][2];
#pragma unroll
    for (int q = 0; q < 5; ++q) {
      if (DO0) acc[q][0] = (float4v){bg[q], bg[q], bg[q], bg[q]};
      if (DO1) acc[q][1] = (float4v){bg[q], bg[q], bg[q], bg[q]};
    }
    const short8 z8 = (short8){0, 0, 0, 0, 0, 0, 0, 0};
#pragma unroll
    for (int kk = 0; kk < 8; ++kk) {
      const int up = (kk >= 4) ? 1 : 0;           // kk<4: h_left; kk>=4: h_up
      const int cc = (kk & 3) * 32 + quad * 8;
      short8 a0, a1;
      if (DO0) {
        int row = col - up;
        a0 = (row >= 0) ? *(const short8*)&h_buf[rbuf][row][cc] : z8;
      }
      if (DO1) {
        int row = 16 + col - up;
        a1 = *(const short8*)&h_buf[rbuf][row][cc];
      }
#pragma unroll
      for (int q = 0; q < 5; ++q) {
        short8 bf;
        if (q < 3) bf = W8[((q * 8 + g) * 8 + kk) * 64 + lane];          // L2 stream
        else       bf = *(const short8*)&wlds[(((q - 3) * 8 + g) * 8 + kk) * 512 + lane * 8];  // LDS
        if (DO0) acc[q][0] = __builtin_amdgcn_mfma_f32_16x16x32_bf16(a0, bf, acc[q][0], 0, 0, 0);
        if (DO1) acc[q][1] = __builtin_amdgcn_mfma_f32_16x16x32_bf16(a1, bf, acc[q][1], 0, 0, 0);
      }
    }

    // ---- epilogue: c_up exchange (old values), hoisted feat+x loads ----
    float t0 = __shfl_up(cp[0][3], 16);
    float t1 = __shfl_up(cp[1][3], 16);
    float tx = __shfl(cp[0][3], col48);            // quad3's row-15 c
    float cuA[4] = {quad ? t0 : 0.0f, cp[0][0], cp[0][1], cp[0][2]};
    float cuB[4] = {quad ? t1 : tx,   cp[1][0], cp[1][1], cp[1][2]};

    float fo[2][4], xm[2][4];
#pragma unroll
    for (int mt = 0; mt < 2; ++mt) {
      if ((mt == 0 && !DO0) || (mt == 1 && !DO1)) continue;
      const int m0 = mt * 16 + quad * 4;
#pragma unroll
      for (int r = 0; r < 4; ++r) {
        int w = d - (m0 + r);
        if (ALLV || (w >= 0 && w < 256)) {
          fo[mt][r] = fb[w * 128 + jj];            // early L2 loads
          xm[mt][r] = Xg[w * 32 + (m0 + r)];
        }
      }
    }
#pragma unroll
    for (int mt = 0; mt < 2; ++mt) {
      if ((mt == 0 && !DO0) || (mt == 1 && !DO1)) continue;
      const int m0 = mt * 16 + quad * 4;
#pragma unroll
      for (int r = 0; r < 4; ++r) {
        const int m = m0 + r;          // C/D layout: row = quad*4 + reg
        const int w = d - m;
        if (ALLV || (w >= 0 && w < 256)) {
          float c_up = mt ? cuB[r] : cuA[r];
          float c_l  = cp[mt][r];
          float x    = xm[mt][r];
          float zi = fmaf(x, wx[0], acc[0][mt][r]);
          float zg = fmaf(x, wx[1], acc[1][mt][r]);
          float z1 = fmaf(x, wx[2], acc[2][mt][r]);
          float z2 = fmaf(x, wx[3], acc[3][mt][r]);
          float zo = fmaf(x, wx[4], acc[4][mt][r]);
          float c = sigf(z1) * c_l + sigf(z2) * c_up + sigf(zi) * tanhfast(zg);
          float h = sigf(zo) * tanhfast(c);
          cp[mt][r] = c;
          h_buf[wbuf][m][jj] = f2bf(h);
          fb[w * 128 + jj] = fo[mt][r] + h;        // unique (w,jj) per lane per diag
        }
      }
    }
  };

  BC<true> T; BC<false> F;
  for (int d = 0;   d < 16;  ++d) { step(d, T, F, F); __syncthreads(); }
  for (int d = 16;  d < 31;  ++d) { step(d, T, T, F); __syncthreads(); }
  for (int d = 31;  d < 256; ++d) { step(d, T, T, T); __syncthreads(); }  // no bounds checks
  for (int d = 256; d < 271; ++d) { step(d, T, T, F); __syncthreads(); }
  for (int d = 271; d < 287; ++d) { step(d, F, T, F); __syncthreads(); }
}

// ---------------------------------------------------------------------------
// logits = feat @ W_fc + b_fc, then log_softmax -> logp [32][256][101]
__global__ __launch_bounds__(256)
void logits_kernel(const float* __restrict__ feat, const float* __restrict__ Wfc,
                   const float* __restrict__ bfc, float* __restrict__ logp) {
  __shared__ float sW[128 * 101];
  __shared__ float sF[8][128];
  __shared__ float sL[8][104];
  __shared__ float sLse[8];
  const int tid = threadIdx.x;
  const int b  = blockIdx.x >> 5;
  const int t0 = (blockIdx.x & 31) * 8;

  for (int i = tid; i < 128 * 101; i += 256) sW[i] = Wfc[i];
  for (int i = tid; i < 8 * 128; i += 256)
    sF[i >> 7][i & 127] = feat[(b * 256 + t0 + (i >> 7)) * 128 + (i & 127)];
  __syncthreads();
  for (int idx = tid; idx < 8 * 101; idx += 256) {
    int tr = idx / 101, v = idx - tr * 101;
    float s = bfc[v];
#pragma unroll 4
    for (int k = 0; k < 128; ++k) s += sF[tr][k] * sW[k * 101 + v];
    sL[tr][v] = s;
  }
  __syncthreads();
  if (tid < 8) {
    float m = NEGF;
    for (int v = 0; v < 101; ++v) m = fmaxf(m, sL[tid][v]);
    float su = 0.0f;
    for (int v = 0; v < 101; ++v) su += __expf(sL[tid][v] - m);
    sLse[tid] = m + __logf(su);
  }
  __syncthreads();
  for (int idx = tid; idx < 8 * 101; idx += 256) {
    int tr = idx / 101, v = idx - tr * 101;
    logp[(b * 256 + t0 + tr) * 101 + v] = sL[tr][v] - sLse[tr];
  }
}

// ---------------------------------------------------------------------------
// CTC forward: one wave per batch. Lane l holds alpha[s=l]; lane 63 also s=64.
// 4-deep rotating prefetch (unroll 4 -> static slot indices, regs not scratch)
// hides the ~300-cyc L2 latency that serialized the old loop.
__global__ __launch_bounds__(64)
void ctc_kernel(const float* __restrict__ logp, const int* __restrict__ y,
                float* __restrict__ out) {
  const int b = blockIdx.x;
  const int l = threadIdx.x;
  const float* lpb = logp + b * 256 * 101;
  const int* yb = y + b * 32;
  int lab = (l & 1) ? yb[l >> 1] : 100;                 // ext[s]: odd->label, even->blank
  bool skip = (l & 1) && (l >= 3) && (yb[l >> 1] != yb[(l >> 1) - 1]);

  float a   = (l == 0) ? lpb[100] : ((l == 1) ? lpb[lab] : NEGF);
  float a64 = NEGF;                                      // alpha[64] (valid on lane 63)
  float pl[4], pb[4];
#pragma unroll
  for (int tt = 0; tt < 4; ++tt) {
    pl[tt] = lpb[(1 + tt) * 101 + lab];
    pb[tt] = lpb[(1 + tt) * 101 + 100];
  }
#pragma unroll 4
  for (int t = 1; t < 256; ++t) {
    const int s = (t - 1) & 3;
    float lpl = pl[s], lpbk = pb[s];
    if (t + 4 < 256) {                                   // refill slot with t+4
      pl[s] = lpb[(t + 4) * 101 + lab];
      pb[s] = lpb[(t + 4) * 101 + 100];
    }
    float am1 = __shfl_up(a, 1); if (l == 0) am1 = NEGF;
    float am2 = __shfl_up(a, 2); if (l < 2 || !skip) am2 = NEGF;
    float m3 = fmaxf(a, fmaxf(am1, am2));
    float na = m3 + __logf(__expf(a - m3) + __expf(am1 - m3) + __expf(am2 - m3)) + lpl;
    float m2 = fmaxf(a64, a);                            // s=64: lse(alpha64, alpha63)
    float na64 = m2 + __logf(__expf(a64 - m2) + __expf(a - m2)) + lpbk;
    a = na;
    a64 = na64;
  }
  float A63 = __shfl(a, 63);
  float A64 = __shfl(a64, 63);
  if (l == 0) {
    float m = fmaxf(A63, A64);
    out[b] = -(m + __logf(__expf(A63 - m) + __expf(A64 - m)));
  }
}

// ---------------------------------------------------------------------------
extern "C" void kernel_launch(void* const* d_in, const int* in_sizes, int n_in,
                              void* d_out, int out_size, void* d_ws, size_t ws_size,
                              hipStream_t stream) {
  const float* X   = (const float*)d_in[0];
  const int*   y   = (const int*)d_in[1];
  const float* Wx  = (const float*)d_in[2];
  const float* Wh1 = (const float*)d_in[3];
  const float* Wh2 = (const float*)d_in[4];
  const float* bi  = (const float*)d_in[5];
  const float* Wfc = (const float*)d_in[6];
  const float* bfc = (const float*)d_in[7];
  float* out = (float*)d_out;

  char* ws = (char*)d_ws;
  short* wsW  = (short*)(ws);              // 327,680 B staged weights
  float* feat = (float*)(ws + 0x50000);    // 4 MiB feat accumulator (zeroed in-kernel)
  float* logp = (float*)(ws + 0x450000);   // 3.31 MB log-probs

  prep_w_kernel<<<80, 256, 0, stream>>>(Wh1, Wh2, wsW);
  mdlstm_kernel<<<32, 512, 0, stream>>>(X, wsW, Wx, bi, feat);
  logits_kernel<<<1024, 256, 0, stream>>>(feat, Wfc, bfc, logp);
  ctc_kernel<<<32, 64, 0, stream>>>(logp, y, out);
}